// Round 7
// baseline (61.872 us; speedup 1.0000x reference)
//
#include <hip/hip_runtime.h>
#include <math.h>

#define BB   512
#define CC   3
#define HH   64
#define WW   32
#define HOUT 38
#define WOUT 16
#define HID  128
#define DD   114               // CC*HOUT
#define SEQP 120               // seq row pad: two 60-float (15 f4) halves
#define WIHP 120               // Wih LDS row pad (words); 480B rows, 16B-aligned
#define WHHP 132               // Whh LDS row pad (words); stride 132%32=4 -> banks spread
#define NPOOL (CC*HOUT*WOUT)   // 1824

typedef float f32x4 __attribute__((ext_vector_type(4)));

// ws layout (floats)
#define WS_SMEAN 0
#define WS_TMEAN 512

// ---- fused per-batch kernel ------------------------------------------------
// 256 threads = 4 waves. tid = (half<<7)|k ; waves 0-1 are half0 (k=0..127),
// waves 2-3 are half1. Weight staging is coalesced global->LDS->regs.
// Projection: split-K across halves (one Zl exchange). Recurrence: half0
// threads hold the FULL Whh row (32 f4) -> one barrier per step.
__global__ __launch_bounds__(256, 2)
void k1_fused(const float* __restrict__ x,
              const float* __restrict__ Wih,
              const float* __restrict__ Whh,
              const float* __restrict__ bih,
              const float* __restrict__ bhh,
              float* __restrict__ s_mean,
              float* __restrict__ t_mean)
{
    __shared__ __align__(16) float wst[HID * WIHP];  // 61.4 KB; x / Wih / Whh-chunks
    __shared__ __align__(16) float seq[WOUT][SEQP];  // 7.7 KB
    __shared__ __align__(16) float Zl[WOUT][HID];    // 8 KB
    __shared__ __align__(16) float hbuf[2][HID];     // 1 KB
    __shared__ float red[4];
    __shared__ int   rowl[HOUT];

    const int tid  = threadIdx.x;
    const int half = tid >> 7;
    const int k    = tid & 127;
    const int wid  = tid >> 6;
    const int lane = tid & 63;
    const int b    = blockIdx.x;

    // fractional-pool row starts (exact IEEE-f64 numpy match)
    if (tid < HOUT) {
        double alpha = (double)(HH - 2) / (double)(HOUT - 1);
        rowl[tid] = (tid < HOUT - 1)
            ? (int)(floor((tid + 0.5) * alpha) - floor(0.5 * alpha))
            : (HH - 2);
    }
    if (tid < HID) hbuf[0][tid] = 0.f;
    if (tid < 96)  seq[tid / 6][DD + tid % 6] = 0.f;   // zero pad cols [114,120)

    // --- stage x[b] into wst (coalesced f4) ---
    {
        const f32x4* xg = (const f32x4*)(x + (size_t)b * (CC*HH*WW));
        f32x4*       xd = (f32x4*)wst;
        #pragma unroll
        for (int i = 0; i < (CC*HH*WW/4)/256; ++i)
            xd[tid + 256*i] = xg[tid + 256*i];
    }
    __syncthreads();                                   // B1

    // --- pool (2x2 fractional max) + exact GELU -> seq; spatial sum ---
    float ps = 0.f;
    #pragma unroll
    for (int it = 0; it < 8; ++it) {
        int idx = tid + it*256;
        if (idx < NPOOL) {
            int c  = idx / (HOUT*WOUT);
            int r  = idx % (HOUT*WOUT);
            int ho = r / WOUT;
            int wo = r % WOUT;
            const float* p0 = &wst[c*(HH*WW) + rowl[ho]*WW + 2*wo];
            float m = fmaxf(fmaxf(p0[0], p0[1]), fmaxf(p0[WW], p0[WW+1]));
            ps += m;
            seq[wo][c*HOUT + ho] =
                0.5f * m * (1.f + erff(m * 0.70710678118654752440f));
        }
    }
    // wave-level reduce (64 lanes), then 4 partials
    #pragma unroll
    for (int off = 32; off > 0; off >>= 1) ps += __shfl_down(ps, off);
    if (lane == 0) red[wid] = ps;
    __syncthreads();                                   // B2 (x reads done; wst reusable)
    if (tid == 0)
        s_mean[b] = (red[0] + red[1] + red[2] + red[3]) * (1.f / (float)NPOOL);

    // --- Wih: one coalesced round into padded rows [128][120] ---
    {
        const f32x4* g4 = (const f32x4*)Wih;
        for (int j4 = tid; j4 < (HID*DD)/4; j4 += 256) {
            f32x4 v = g4[j4];
            int j = j4 * 4;
            #pragma unroll
            for (int e = 0; e < 4; ++e) {
                int r  = (j + e) / DD;
                int cc = (j + e) - r*DD;
                wst[r*WIHP + cc] = v[e];
            }
        }
        for (int j = tid; j < HID*6; j += 256)         // zero cols [114,120)
            wst[(j/6)*WIHP + DD + (j % 6)] = 0.f;
    }
    __syncthreads();                                   // B3
    f32x4 wih[15];
    {
        const f32x4* wr = (const f32x4*)&wst[k*WIHP + half*60];  // 16B-aligned
        #pragma unroll
        for (int dd = 0; dd < 15; ++dd) wih[dd] = wr[dd];
    }

    // --- projection (split-K): zp = seq[t][half*60 .. +60) . wih ---
    float zreg[WOUT];
    #pragma unroll
    for (int t = 0; t < WOUT; ++t) {
        const f32x4* a4 = (const f32x4*)&seq[t][half*60];  // wave-uniform bcast
        float s0 = 0.f, s1 = 0.f, s2 = 0.f, s3 = 0.f;
        #pragma unroll
        for (int dd = 0; dd < 15; ++dd) {
            f32x4 a = a4[dd];
            s0 = fmaf(wih[dd].x, a.x, s0);
            s1 = fmaf(wih[dd].y, a.y, s1);
            s2 = fmaf(wih[dd].z, a.z, s2);
            s3 = fmaf(wih[dd].w, a.w, s3);
        }
        float zp = (s0 + s1) + (s2 + s3);
        if (half) Zl[t][k] = zp; else zreg[t] = zp;
    }
    __syncthreads();                                   // B4 (Zl visible; wih/wst dead)
    {
        const float bias = bih[k] + bhh[k];
        if (!half) {
            #pragma unroll
            for (int t = 0; t < WOUT; ++t) zreg[t] += bias + Zl[t][k];
        }
    }

    // --- Whh: 2 coalesced chunks of 64 rows into padded rows [64][132] ---
    f32x4 whh[32];
    #pragma unroll
    for (int c = 0; c < 2; ++c) {
        const f32x4* g4 = (const f32x4*)(Whh + c*64*HID);
        for (int j4 = tid; j4 < (64*HID)/4; j4 += 256) {
            int r  = j4 >> 5;                          // 32 f4 per source row
            int c4 = j4 & 31;
            *(f32x4*)&wst[r*WHHP + (c4 << 2)] = g4[j4];
        }
        __syncthreads();                               // B5 / B7
        if (!half && (k >> 6) == c) {
            const f32x4* wr = (const f32x4*)&wst[(k & 63)*WHHP];
            #pragma unroll
            for (int dd = 0; dd < 32; ++dd) whh[dd] = wr[dd];
        }
        __syncthreads();                               // B6 / B8
    }

    // --- 16-step recurrence: half0 full-row dot, ONE barrier per step ---
    float hsum = 0.f;
    #pragma unroll
    for (int t = 0; t < WOUT; ++t) {
        if (!half) {
            const f32x4* h4 = (const f32x4*)hbuf[t & 1];   // wave-uniform bcast
            float s0 = 0.f, s1 = 0.f, s2 = 0.f, s3 = 0.f;
            #pragma unroll
            for (int dd = 0; dd < 32; ++dd) {
                f32x4 hv = h4[dd];
                s0 = fmaf(whh[dd].x, hv.x, s0);
                s1 = fmaf(whh[dd].y, hv.y, s1);
                s2 = fmaf(whh[dd].z, hv.z, s2);
                s3 = fmaf(whh[dd].w, hv.w, s3);
            }
            float hn = tanhf(zreg[t] + ((s0 + s1) + (s2 + s3)));
            hsum += hn;
            hbuf[(t + 1) & 1][k] = hn;
        }
        __syncthreads();                               // one per step
    }
    if (!half) t_mean[b*HID + k] = tanhf(hsum * (1.f / 16.f));
}

// ---- k2: out[i,0,j,kk] = s_mean[i] * t_mean[j,kk]  (plain streaming stores) -
__global__ __launch_bounds__(256)
void k2_out(const float* __restrict__ s_mean,
            const float* __restrict__ t_mean,
            f32x4* __restrict__ out)
{
    const int total = BB * BB * HID / 4;        // 8,388,608 f4
    const f32x4* t4 = (const f32x4*)t_mean;
    const int stride = gridDim.x * blockDim.x;
    for (int g = blockIdx.x * blockDim.x + threadIdx.x; g < total; g += stride) {
        int i = g >> 14;                        // 16384 f4 per i
        int r = g & 16383;
        float s = s_mean[i];
        f32x4 t = t4[r];
        out[g] = s * t;
    }
}

extern "C" void kernel_launch(void* const* d_in, const int* in_sizes, int n_in,
                              void* d_out, int out_size, void* d_ws, size_t ws_size,
                              hipStream_t stream)
{
    const float* x   = (const float*)d_in[0];
    const float* Wih = (const float*)d_in[1];
    const float* Whh = (const float*)d_in[2];
    const float* bih = (const float*)d_in[3];
    const float* bhh = (const float*)d_in[4];

    float* ws     = (float*)d_ws;
    float* s_mean = ws + WS_SMEAN;
    float* t_mean = ws + WS_TMEAN;

    k1_fused<<<dim3(BB), dim3(256), 0, stream>>>(x, Wih, Whh, bih, bhh, s_mean, t_mean);
    k2_out  <<<dim3(4096), dim3(256), 0, stream>>>(s_mean, t_mean, (f32x4*)d_out);
}

// Round 8
// 53.755 us; speedup vs baseline: 1.1510x; 1.1510x over previous
//
#include <hip/hip_runtime.h>
#include <math.h>

#define BB   512
#define CC   3
#define HH   64
#define WW   32
#define HOUT 38
#define WOUT 16
#define HID  128
#define DD   114               // CC*HOUT
#define SEQP 120               // seq row pad: two 60-float (15 f4) halves
#define WROW 132               // weight LDS row pad (132 ≡ 4 mod 32 -> 8-way max)
#define NPOOL (CC*HOUT*WOUT)   // 1824

typedef float f32x4 __attribute__((ext_vector_type(4)));

// ws layout (floats)
#define WS_SMEAN 0
#define WS_TMEAN 512

// ---- fused per-batch kernel (R6-proven: VGPR 92, no spill, 53.8 us total) --
// 256 threads: tid = (half<<7)|k. Thread (k,half) holds half of Wih row k
// (15 f4) and half of Whh row k (16 f4) in registers; weights arrive via
// COALESCED global->LDS staging (4 chunks of 64 rows through a 33 KB buffer
// that reuses the x-staging region), never via lane-divergent gathers.
__global__ __launch_bounds__(256, 2)
void k1_fused(const float* __restrict__ x,
              const float* __restrict__ Wih,
              const float* __restrict__ Whh,
              const float* __restrict__ bih,
              const float* __restrict__ bhh,
              float* __restrict__ s_mean,
              float* __restrict__ t_mean)
{
    __shared__ __align__(16) float wst[64 * WROW];   // 33 KB; also x-stage region
    __shared__ __align__(16) float seq[WOUT][SEQP];  // 7.5 KB
    __shared__ __align__(16) float Zl[WOUT][HID];    // 8 KB
    __shared__ __align__(16) float hbuf[2][HID];     // 1 KB
    __shared__ float psum[HID];
    __shared__ float red[256];
    __shared__ int   rowl[HOUT];

    const int tid  = threadIdx.x;
    const int half = tid >> 7;
    const int k    = tid & 127;
    const int b    = blockIdx.x;

    // fractional-pool row starts (exact IEEE-f64 numpy match)
    if (tid < HOUT) {
        double alpha = (double)(HH - 2) / (double)(HOUT - 1);
        rowl[tid] = (tid < HOUT - 1)
            ? (int)(floor((tid + 0.5) * alpha) - floor(0.5 * alpha))
            : (HH - 2);
    }
    if (tid < HID) hbuf[0][tid] = 0.f;
    if (tid < 96)  seq[tid / 6][DD + tid % 6] = 0.f;  // zero pad lanes [114,120)

    // --- stage x[b] into wst (coalesced f4) ---
    {
        const f32x4* xg = (const f32x4*)(x + (size_t)b * (CC*HH*WW));
        f32x4*       xd = (f32x4*)wst;
        #pragma unroll
        for (int i = 0; i < (CC*HH*WW/4)/256; ++i)
            xd[tid + 256*i] = xg[tid + 256*i];
    }
    __syncthreads();

    // --- pool (2x2 fractional max) + exact GELU -> seq; spatial sum ---
    float ps = 0.f;
    #pragma unroll
    for (int it = 0; it < 8; ++it) {
        int idx = tid + it*256;
        if (idx < NPOOL) {
            int c  = idx / (HOUT*WOUT);
            int r  = idx % (HOUT*WOUT);
            int ho = r / WOUT;
            int wo = r % WOUT;
            const float* p0 = &wst[c*(HH*WW) + rowl[ho]*WW + 2*wo];
            float m = fmaxf(fmaxf(p0[0], p0[1]), fmaxf(p0[WW], p0[WW+1]));
            ps += m;
            seq[wo][c*HOUT + ho] =
                0.5f * m * (1.f + erff(m * 0.70710678118654752440f));
        }
    }
    red[tid] = ps;
    __syncthreads();
    #pragma unroll
    for (int s = 128; s > 0; s >>= 1) {
        if (tid < s) red[tid] += red[tid + s];
        __syncthreads();
    }
    if (tid == 0) s_mean[b] = red[0] / (float)NPOOL;
    __syncthreads();   // wst (x copy) now dead; safe to reuse for weights

    // --- weights: coalesced global -> LDS chunks -> registers ---
    f32x4 wih[15];
    f32x4 whh[16];

    #pragma unroll
    for (int c = 0; c < 2; ++c) {          // Wih rows [64c, 64c+64)
        const f32x4* g4 = (const f32x4*)(Wih + c*64*DD);
        for (int j4 = tid; j4 < (64*DD)/4; j4 += 256) {
            f32x4 v = g4[j4];
            int j = 4*j4;
            #pragma unroll
            for (int e = 0; e < 4; ++e) {
                int r  = (j + e) / DD;     // const-div -> magic mul
                int cc = (j + e) - r*DD;
                wst[r*WROW + cc] = v[e];
            }
        }
        for (int j = tid; j < 64*6; j += 256)        // zero cols [114,120)
            wst[(j/6)*WROW + DD + (j % 6)] = 0.f;
        __syncthreads();
        if ((k >> 6) == c) {
            const f32x4* wr = (const f32x4*)&wst[(k & 63)*WROW + half*60];
            #pragma unroll
            for (int dd = 0; dd < 15; ++dd) wih[dd] = wr[dd];
        }
        __syncthreads();
    }
    #pragma unroll
    for (int c = 0; c < 2; ++c) {          // Whh rows [64c, 64c+64)
        const f32x4* g4 = (const f32x4*)(Whh + c*64*HID);
        for (int j4 = tid; j4 < (64*HID)/4; j4 += 256) {
            int r  = j4 >> 5;              // 32 f4 per row
            int c4 = j4 & 31;
            *(f32x4*)&wst[r*WROW + (c4 << 2)] = g4[j4];
        }
        __syncthreads();
        if ((k >> 6) == c) {
            const f32x4* wr = (const f32x4*)&wst[(k & 63)*WROW + (half << 6)];
            #pragma unroll
            for (int dd = 0; dd < 16; ++dd) whh[dd] = wr[dd];
        }
        __syncthreads();
    }

    // --- projection: z[t] (kept in half-0 registers) ---
    float zreg[WOUT];
    #pragma unroll
    for (int t = 0; t < WOUT; ++t) {
        const f32x4* a4 = (const f32x4*)&seq[t][half*60];  // wave-uniform bcast
        float s0 = 0.f, s1 = 0.f, s2 = 0.f, s3 = 0.f;
        #pragma unroll
        for (int dd = 0; dd < 15; ++dd) {
            f32x4 a = a4[dd];
            s0 = fmaf(wih[dd].x, a.x, s0);
            s1 = fmaf(wih[dd].y, a.y, s1);
            s2 = fmaf(wih[dd].z, a.z, s2);
            s3 = fmaf(wih[dd].w, a.w, s3);
        }
        float zp = (s0 + s1) + (s2 + s3);
        if (half) Zl[t][k] = zp; else zreg[t] = zp;
    }
    __syncthreads();
    const float bias = bih[k] + bhh[k];    // lane-consecutive, coalesced
    if (!half) {
        #pragma unroll
        for (int t = 0; t < WOUT; ++t) zreg[t] += bias + Zl[t][k];
    }

    // --- 16-step recurrence (split-K; h broadcast from LDS) ---
    float hsum = 0.f;
    #pragma unroll
    for (int t = 0; t < WOUT; ++t) {
        const int cur = t & 1, nxt = cur ^ 1;
        const f32x4* h4 = (const f32x4*)&hbuf[cur][half << 6];  // bcast
        float s0 = 0.f, s1 = 0.f, s2 = 0.f, s3 = 0.f;
        #pragma unroll
        for (int dd = 0; dd < 16; ++dd) {
            f32x4 hv = h4[dd];
            s0 = fmaf(whh[dd].x, hv.x, s0);
            s1 = fmaf(whh[dd].y, hv.y, s1);
            s2 = fmaf(whh[dd].z, hv.z, s2);
            s3 = fmaf(whh[dd].w, hv.w, s3);
        }
        float up = (s0 + s1) + (s2 + s3);
        if (half) psum[k] = up;
        __syncthreads();
        if (!half) {
            float hn = tanhf(zreg[t] + up + psum[k]);
            hsum += hn;
            hbuf[nxt][k] = hn;
        }
        __syncthreads();
    }
    if (!half) t_mean[b*HID + k] = tanhf(hsum * (1.f / 16.f));
}

// ---- k2: block (i, sub) writes out[i, 0, sub*2048 .. +2048) f4 -------------
// s_mean[i] is wave-uniform (scalar load, hoisted); t_mean/out fully coalesced.
__global__ __launch_bounds__(256)
void k2_out(const float* __restrict__ s_mean,
            const float* __restrict__ t_mean,
            f32x4* __restrict__ out)
{
    const int i   = blockIdx.x >> 3;           // batch row (512)
    const int sub = blockIdx.x & 7;            // eighth of a row
    const float s = s_mean[i];
    const f32x4* t4 = (const f32x4*)t_mean + sub*2048;
    f32x4*       o  = out + (size_t)i*16384 + sub*2048;
    const int tid = threadIdx.x;
    #pragma unroll
    for (int j = 0; j < 8; ++j) {
        int idx = tid + j*256;
        o[idx] = s * t4[idx];
    }
}

extern "C" void kernel_launch(void* const* d_in, const int* in_sizes, int n_in,
                              void* d_out, int out_size, void* d_ws, size_t ws_size,
                              hipStream_t stream)
{
    const float* x   = (const float*)d_in[0];
    const float* Wih = (const float*)d_in[1];
    const float* Whh = (const float*)d_in[2];
    const float* bih = (const float*)d_in[3];
    const float* bhh = (const float*)d_in[4];

    float* ws     = (float*)d_ws;
    float* s_mean = ws + WS_SMEAN;
    float* t_mean = ws + WS_TMEAN;

    k1_fused<<<dim3(BB), dim3(256), 0, stream>>>(x, Wih, Whh, bih, bhh, s_mean, t_mean);
    k2_out  <<<dim3(4096), dim3(256), 0, stream>>>(s_mean, t_mean, (f32x4*)d_out);
}

// Round 9
// 52.248 us; speedup vs baseline: 1.1842x; 1.0288x over previous
//
#include <hip/hip_runtime.h>
#include <math.h>

#define BB   512
#define CC   3
#define HH   64
#define WW   32
#define HOUT 38
#define WOUT 16
#define HID  128
#define DD   114               // CC*HOUT
#define SEQP 120               // seq row pad: two 60-float (15 f4) halves
#define WIHP 120               // Wih LDS row pad (words), 16B-aligned rows
#define WHHP 132               // Whh LDS row pad (words); 132%32=4 -> banks spread
#define NPOOL (CC*HOUT*WOUT)   // 1824

typedef float f32x4 __attribute__((ext_vector_type(4)));

// fast tanh on the serial chain: exact saturation at +/-inf, ~1e-6 abs error
__device__ __forceinline__ float fast_tanh(float u) {
    return 1.f - 2.f / (__expf(2.f * u) + 1.f);
}

// ws layout (floats)
#define WS_SMEAN 0
#define WS_TMEAN 512

// ---- fused per-batch kernel ------------------------------------------------
// 256 threads: tid = (half<<7)|k. Thread (k,half) holds half of Wih row k
// (15 f4) and half of Whh row k (16 f4) in registers (92 VGPR proven, no
// spill). Weights arrive via COALESCED global->LDS staging; Wih in ONE round
// (61 KB padded region), Whh in 2 chunks. s_mean via wave shfl-reduce.
__global__ __launch_bounds__(256, 2)
void k1_fused(const float* __restrict__ x,
              const float* __restrict__ Wih,
              const float* __restrict__ Whh,
              const float* __restrict__ bih,
              const float* __restrict__ bhh,
              float* __restrict__ s_mean,
              float* __restrict__ t_mean)
{
    __shared__ __align__(16) float wst[HID * WIHP];  // 61.4 KB; x / Wih / Whh-chunks
    __shared__ __align__(16) float seq[WOUT][SEQP];  // 7.7 KB
    __shared__ __align__(16) float Zl[WOUT][HID];    // 8 KB
    __shared__ __align__(16) float hbuf[2][HID];     // 1 KB
    __shared__ float psum[HID];
    __shared__ float red[4];
    __shared__ int   rowl[HOUT];

    const int tid  = threadIdx.x;
    const int half = tid >> 7;
    const int k    = tid & 127;
    const int wid  = tid >> 6;
    const int lane = tid & 63;
    const int b    = blockIdx.x;

    // fractional-pool row starts (exact IEEE-f64 numpy match)
    if (tid < HOUT) {
        double alpha = (double)(HH - 2) / (double)(HOUT - 1);
        rowl[tid] = (tid < HOUT - 1)
            ? (int)(floor((tid + 0.5) * alpha) - floor(0.5 * alpha))
            : (HH - 2);
    }
    if (tid < HID) hbuf[0][tid] = 0.f;
    if (tid < 96)  seq[tid / 6][DD + tid % 6] = 0.f;  // zero pad cols [114,120)

    // --- stage x[b] into wst (coalesced f4) ---
    {
        const f32x4* xg = (const f32x4*)(x + (size_t)b * (CC*HH*WW));
        f32x4*       xd = (f32x4*)wst;
        #pragma unroll
        for (int i = 0; i < (CC*HH*WW/4)/256; ++i)
            xd[tid + 256*i] = xg[tid + 256*i];
    }
    __syncthreads();                                  // B1

    // --- pool (2x2 fractional max) + exact GELU -> seq; spatial sum ---
    float ps = 0.f;
    #pragma unroll
    for (int it = 0; it < 8; ++it) {
        int idx = tid + it*256;
        if (idx < NPOOL) {
            int c  = idx / (HOUT*WOUT);
            int r  = idx % (HOUT*WOUT);
            int ho = r / WOUT;
            int wo = r % WOUT;
            const float* p0 = &wst[c*(HH*WW) + rowl[ho]*WW + 2*wo];
            float m = fmaxf(fmaxf(p0[0], p0[1]), fmaxf(p0[WW], p0[WW+1]));
            ps += m;
            seq[wo][c*HOUT + ho] =
                0.5f * m * (1.f + erff(m * 0.70710678118654752440f));
        }
    }
    // wave shfl-reduce, then 4 partials (replaces 9-barrier tree)
    #pragma unroll
    for (int off = 32; off > 0; off >>= 1) ps += __shfl_down(ps, off);
    if (lane == 0) red[wid] = ps;
    __syncthreads();                                  // B2 (also: x reads done)
    if (tid == 0)
        s_mean[b] = (red[0] + red[1] + red[2] + red[3]) * (1.f / (float)NPOOL);

    // --- Wih: ONE coalesced round into padded rows [128][120] ---
    {
        const f32x4* g4 = (const f32x4*)Wih;
        for (int j4 = tid; j4 < (HID*DD)/4; j4 += 256) {
            f32x4 v = g4[j4];
            int j = 4*j4;
            #pragma unroll
            for (int e = 0; e < 4; ++e) {
                int r  = (j + e) / DD;                // const-div -> magic mul
                int cc = (j + e) - r*DD;
                wst[r*WIHP + cc] = v[e];
            }
        }
        for (int j = tid; j < HID*6; j += 256)        // zero cols [114,120)
            wst[(j/6)*WIHP + DD + (j % 6)] = 0.f;
    }
    __syncthreads();                                  // B3
    f32x4 wih[15];
    {
        const f32x4* wr = (const f32x4*)&wst[k*WIHP + half*60];
        #pragma unroll
        for (int dd = 0; dd < 15; ++dd) wih[dd] = wr[dd];
    }

    // --- projection: z[t] (kept in half-0 registers) ---
    float zreg[WOUT];
    #pragma unroll
    for (int t = 0; t < WOUT; ++t) {
        const f32x4* a4 = (const f32x4*)&seq[t][half*60];  // wave-uniform bcast
        float s0 = 0.f, s1 = 0.f, s2 = 0.f, s3 = 0.f;
        #pragma unroll
        for (int dd = 0; dd < 15; ++dd) {
            f32x4 a = a4[dd];
            s0 = fmaf(wih[dd].x, a.x, s0);
            s1 = fmaf(wih[dd].y, a.y, s1);
            s2 = fmaf(wih[dd].z, a.z, s2);
            s3 = fmaf(wih[dd].w, a.w, s3);
        }
        float zp = (s0 + s1) + (s2 + s3);
        if (half) Zl[t][k] = zp; else zreg[t] = zp;
    }
    __syncthreads();                                  // B4 (Zl visible; wst dead)
    {
        const float bias = bih[k] + bhh[k];
        if (!half) {
            #pragma unroll
            for (int t = 0; t < WOUT; ++t) zreg[t] += bias + Zl[t][k];
        }
    }

    // --- Whh: 2 coalesced chunks of 64 rows into padded rows [64][132] ---
    f32x4 whh[16];
    #pragma unroll
    for (int c = 0; c < 2; ++c) {
        const f32x4* g4 = (const f32x4*)(Whh + c*64*HID);
        for (int j4 = tid; j4 < (64*HID)/4; j4 += 256) {
            int r  = j4 >> 5;                         // 32 f4 per source row
            int c4 = j4 & 31;
            *(f32x4*)&wst[r*WHHP + (c4 << 2)] = g4[j4];
        }
        __syncthreads();                              // B5 / B7
        if ((k >> 6) == c) {
            const f32x4* wr = (const f32x4*)&wst[(k & 63)*WHHP + (half << 6)];
            #pragma unroll
            for (int dd = 0; dd < 16; ++dd) whh[dd] = wr[dd];
        }
        __syncthreads();                              // B6 / B8
    }

    // --- 16-step recurrence (split-K; h broadcast from LDS) ---
    float hsum = 0.f;
    #pragma unroll
    for (int t = 0; t < WOUT; ++t) {
        const int cur = t & 1, nxt = cur ^ 1;
        const f32x4* h4 = (const f32x4*)&hbuf[cur][half << 6];  // bcast
        float s0 = 0.f, s1 = 0.f, s2 = 0.f, s3 = 0.f;
        #pragma unroll
        for (int dd = 0; dd < 16; ++dd) {
            f32x4 hv = h4[dd];
            s0 = fmaf(whh[dd].x, hv.x, s0);
            s1 = fmaf(whh[dd].y, hv.y, s1);
            s2 = fmaf(whh[dd].z, hv.z, s2);
            s3 = fmaf(whh[dd].w, hv.w, s3);
        }
        float up = (s0 + s1) + (s2 + s3);
        if (half) psum[k] = up;
        __syncthreads();                              // exchange
        if (!half) {
            float hn = fast_tanh(zreg[t] + up + psum[k]);
            hsum += hn;
            hbuf[nxt][k] = hn;
        }
        __syncthreads();                              // h publish
    }
    if (!half) t_mean[b*HID + k] = fast_tanh(hsum * (1.f / 16.f));
}

// ---- k2: block (i, sub) writes out[i, 0, sub*2048 .. +2048) f4 -------------
__global__ __launch_bounds__(256)
void k2_out(const float* __restrict__ s_mean,
            const float* __restrict__ t_mean,
            f32x4* __restrict__ out)
{
    const int i   = blockIdx.x >> 3;           // batch row (512)
    const int sub = blockIdx.x & 7;            // eighth of a row
    const float s = s_mean[i];
    const f32x4* t4 = (const f32x4*)t_mean + sub*2048;
    f32x4*       o  = out + (size_t)i*16384 + sub*2048;
    const int tid = threadIdx.x;
    #pragma unroll
    for (int j = 0; j < 8; ++j) {
        int idx = tid + j*256;
        o[idx] = s * t4[idx];
    }
}

extern "C" void kernel_launch(void* const* d_in, const int* in_sizes, int n_in,
                              void* d_out, int out_size, void* d_ws, size_t ws_size,
                              hipStream_t stream)
{
    const float* x   = (const float*)d_in[0];
    const float* Wih = (const float*)d_in[1];
    const float* Whh = (const float*)d_in[2];
    const float* bih = (const float*)d_in[3];
    const float* bhh = (const float*)d_in[4];

    float* ws     = (float*)d_ws;
    float* s_mean = ws + WS_SMEAN;
    float* t_mean = ws + WS_TMEAN;

    k1_fused<<<dim3(BB), dim3(256), 0, stream>>>(x, Wih, Whh, bih, bhh, s_mean, t_mean);
    k2_out  <<<dim3(4096), dim3(256), 0, stream>>>(s_mean, t_mean, (f32x4*)d_out);
}

// Round 10
// 49.818 us; speedup vs baseline: 1.2419x; 1.0488x over previous
//
#include <hip/hip_runtime.h>
#include <math.h>

#define BB   512
#define CC   3
#define HH   64
#define WW   32
#define HOUT 38
#define WOUT 16
#define HID  128
#define DD   114               // CC*HOUT
#define SEQP 120               // seq row pad: two 60-float (15 f4) halves
#define WIHP 120               // Wih LDS row pad (words), 16B-aligned rows
#define WHHP 132               // Whh LDS row pad (words); 132%32=4 -> banks spread
#define NPOOL (CC*HOUT*WOUT)   // 1824

typedef float f32x4 __attribute__((ext_vector_type(4)));

// fast tanh on the serial chain: exact saturation at +/-inf, ~1e-6 abs error
__device__ __forceinline__ float fast_tanh(float u) {
    return 1.f - 2.f / (__expf(2.f * u) + 1.f);
}

// ws layout (floats)
#define WS_SMEAN 0
#define WS_TMEAN 512

// ---- fused per-batch kernel ------------------------------------------------
// R9 structure + T14 async staging: all global loads are issued into registers
// EARLY (hidden under preceding compute); LDS writes happen late from regs.
__global__ __launch_bounds__(256, 2)
void k1_fused(const float* __restrict__ x,
              const float* __restrict__ Wih,
              const float* __restrict__ Whh,
              const float* __restrict__ bih,
              const float* __restrict__ bhh,
              float* __restrict__ s_mean,
              float* __restrict__ t_mean)
{
    __shared__ __align__(16) float wst[HID * WIHP];  // 61.4 KB; x / Wih / Whh-chunks
    __shared__ __align__(16) float seq[WOUT][SEQP];  // 7.7 KB
    __shared__ __align__(16) float Zl[WOUT][HID];    // 8 KB
    __shared__ __align__(16) float hbuf[2][HID];     // 1 KB
    __shared__ float psum[HID];
    __shared__ float red[4];
    __shared__ int   rowl[HOUT];

    const int tid  = threadIdx.x;
    const int half = tid >> 7;
    const int k    = tid & 127;
    const int wid  = tid >> 6;
    const int lane = tid & 63;
    const int b    = blockIdx.x;

    // --- issue x loads FIRST (oldest in vmcnt FIFO), then Wih prefetch ---
    f32x4 xpf[6];
    {
        const f32x4* xg = (const f32x4*)(x + (size_t)b * (CC*HH*WW));
        #pragma unroll
        for (int i = 0; i < 6; ++i) xpf[i] = xg[tid + 256*i];
    }
    f32x4 wihpf[14], wihtail;
    {
        const f32x4* wg = (const f32x4*)Wih;          // 3648 f4 total
        #pragma unroll
        for (int i = 0; i < 14; ++i) wihpf[i] = wg[tid + 256*i];
        if (tid < 64) wihtail = wg[3584 + tid];
    }

    // fractional-pool row starts (exact IEEE-f64 numpy match)
    if (tid < HOUT) {
        double alpha = (double)(HH - 2) / (double)(HOUT - 1);
        rowl[tid] = (tid < HOUT - 1)
            ? (int)(floor((tid + 0.5) * alpha) - floor(0.5 * alpha))
            : (HH - 2);
    }
    if (tid < HID) hbuf[0][tid] = 0.f;
    if (tid < 96)  seq[tid / 6][DD + tid % 6] = 0.f;  // zero pad cols [114,120)

    // --- write x to LDS (waits only on x loads; Wih stays in flight) ---
    {
        f32x4* xd = (f32x4*)wst;
        #pragma unroll
        for (int i = 0; i < 6; ++i) xd[tid + 256*i] = xpf[i];
    }
    __syncthreads();                                  // B1

    // --- pool (2x2 fractional max) + exact GELU -> seq; spatial sum ---
    float ps = 0.f;
    #pragma unroll
    for (int it = 0; it < 8; ++it) {
        int idx = tid + it*256;
        if (idx < NPOOL) {
            int c  = idx / (HOUT*WOUT);
            int r  = idx % (HOUT*WOUT);
            int ho = r / WOUT;
            int wo = r % WOUT;
            const float* p0 = &wst[c*(HH*WW) + rowl[ho]*WW + 2*wo];
            float m = fmaxf(fmaxf(p0[0], p0[1]), fmaxf(p0[WW], p0[WW+1]));
            ps += m;
            seq[wo][c*HOUT + ho] =
                0.5f * m * (1.f + erff(m * 0.70710678118654752440f));
        }
    }
    #pragma unroll
    for (int off = 32; off > 0; off >>= 1) ps += __shfl_down(ps, off);
    if (lane == 0) red[wid] = ps;
    __syncthreads();                                  // B2 (x reads done; wst reusable)
    if (tid == 0)
        s_mean[b] = (red[0] + red[1] + red[2] + red[3]) * (1.f / (float)NPOOL);

    // --- Wih: LDS writes from prefetched regs (loads long since arrived) ---
    #pragma unroll
    for (int i = 0; i < 14; ++i) {
        int j = 4*(tid + 256*i);
        #pragma unroll
        for (int e = 0; e < 4; ++e) {
            int r  = (j + e) / DD;                    // const-div -> magic mul
            int cc = (j + e) - r*DD;
            wst[r*WIHP + cc] = wihpf[i][e];
        }
    }
    if (tid < 64) {
        int j = 4*(3584 + tid);
        #pragma unroll
        for (int e = 0; e < 4; ++e) {
            int r  = (j + e) / DD;
            int cc = (j + e) - r*DD;
            wst[r*WIHP + cc] = wihtail[e];
        }
    }
    for (int j = tid; j < HID*6; j += 256)            // zero cols [114,120)
        wst[(j/6)*WIHP + DD + (j % 6)] = 0.f;
    __syncthreads();                                  // B3

    f32x4 wih[15];
    {
        const f32x4* wr = (const f32x4*)&wst[k*WIHP + half*60];
        #pragma unroll
        for (int dd = 0; dd < 15; ++dd) wih[dd] = wr[dd];
    }

    // --- issue Whh chunk-0 prefetch; latency hides under projection ---
    f32x4 whhpf[8];
    {
        const f32x4* hg = (const f32x4*)Whh;          // rows [0,64): 2048 f4
        #pragma unroll
        for (int i = 0; i < 8; ++i) whhpf[i] = hg[tid + 256*i];
    }

    // --- projection: z[t] (kept in half-0 registers) ---
    float zreg[WOUT];
    #pragma unroll
    for (int t = 0; t < WOUT; ++t) {
        const f32x4* a4 = (const f32x4*)&seq[t][half*60];  // wave-uniform bcast
        float s0 = 0.f, s1 = 0.f, s2 = 0.f, s3 = 0.f;
        #pragma unroll
        for (int dd = 0; dd < 15; ++dd) {
            f32x4 a = a4[dd];
            s0 = fmaf(wih[dd].x, a.x, s0);
            s1 = fmaf(wih[dd].y, a.y, s1);
            s2 = fmaf(wih[dd].z, a.z, s2);
            s3 = fmaf(wih[dd].w, a.w, s3);
        }
        float zp = (s0 + s1) + (s2 + s3);
        if (half) Zl[t][k] = zp; else zreg[t] = zp;
    }
    __syncthreads();                                  // B4 (Zl visible; wst dead)
    {
        const float bias = bih[k] + bhh[k];
        if (!half) {
            #pragma unroll
            for (int t = 0; t < WOUT; ++t) zreg[t] += bias + Zl[t][k];
        }
    }

    // --- Whh chunk 0: ds_write from regs, copy; chunk 1 prefetch under copy ---
    f32x4 whh[16];
    #pragma unroll
    for (int i = 0; i < 8; ++i) {
        int j4 = tid + 256*i;
        *(f32x4*)&wst[(j4 >> 5)*WHHP + ((j4 & 31) << 2)] = whhpf[i];
    }
    __syncthreads();                                  // B5
    if ((k >> 6) == 0) {
        const f32x4* wr = (const f32x4*)&wst[(k & 63)*WHHP + (half << 6)];
        #pragma unroll
        for (int dd = 0; dd < 16; ++dd) whh[dd] = wr[dd];
    }
    {
        const f32x4* hg = (const f32x4*)(Whh + 64*HID);   // rows [64,128)
        #pragma unroll
        for (int i = 0; i < 8; ++i) whhpf[i] = hg[tid + 256*i];
    }
    __syncthreads();                                  // B6 (copies done; buffer free)
    #pragma unroll
    for (int i = 0; i < 8; ++i) {
        int j4 = tid + 256*i;
        *(f32x4*)&wst[(j4 >> 5)*WHHP + ((j4 & 31) << 2)] = whhpf[i];
    }
    __syncthreads();                                  // B7
    if ((k >> 6) == 1) {
        const f32x4* wr = (const f32x4*)&wst[(k & 63)*WHHP + (half << 6)];
        #pragma unroll
        for (int dd = 0; dd < 16; ++dd) whh[dd] = wr[dd];
    }

    // --- 16-step recurrence (split-K; h broadcast from LDS) — R9 verbatim ---
    float hsum = 0.f;
    #pragma unroll
    for (int t = 0; t < WOUT; ++t) {
        const int cur = t & 1, nxt = cur ^ 1;
        const f32x4* h4 = (const f32x4*)&hbuf[cur][half << 6];  // bcast
        float s0 = 0.f, s1 = 0.f, s2 = 0.f, s3 = 0.f;
        #pragma unroll
        for (int dd = 0; dd < 16; ++dd) {
            f32x4 hv = h4[dd];
            s0 = fmaf(whh[dd].x, hv.x, s0);
            s1 = fmaf(whh[dd].y, hv.y, s1);
            s2 = fmaf(whh[dd].z, hv.z, s2);
            s3 = fmaf(whh[dd].w, hv.w, s3);
        }
        float up = (s0 + s1) + (s2 + s3);
        if (half) psum[k] = up;
        __syncthreads();                              // exchange
        if (!half) {
            float hn = fast_tanh(zreg[t] + up + psum[k]);
            hsum += hn;
            hbuf[nxt][k] = hn;
        }
        __syncthreads();                              // h publish
    }
    if (!half) t_mean[b*HID + k] = fast_tanh(hsum * (1.f / 16.f));
}

// ---- k2: block (i, sub) writes out[i, 0, sub*2048 .. +2048) f4 -------------
__global__ __launch_bounds__(256)
void k2_out(const float* __restrict__ s_mean,
            const float* __restrict__ t_mean,
            f32x4* __restrict__ out)
{
    const int i   = blockIdx.x >> 3;           // batch row (512)
    const int sub = blockIdx.x & 7;            // eighth of a row
    const float s = s_mean[i];
    const f32x4* t4 = (const f32x4*)t_mean + sub*2048;
    f32x4*       o  = out + (size_t)i*16384 + sub*2048;
    const int tid = threadIdx.x;
    #pragma unroll
    for (int j = 0; j < 8; ++j) {
        int idx = tid + j*256;
        o[idx] = s * t4[idx];
    }
}

extern "C" void kernel_launch(void* const* d_in, const int* in_sizes, int n_in,
                              void* d_out, int out_size, void* d_ws, size_t ws_size,
                              hipStream_t stream)
{
    const float* x   = (const float*)d_in[0];
    const float* Wih = (const float*)d_in[1];
    const float* Whh = (const float*)d_in[2];
    const float* bih = (const float*)d_in[3];
    const float* bhh = (const float*)d_in[4];

    float* ws     = (float*)d_ws;
    float* s_mean = ws + WS_SMEAN;
    float* t_mean = ws + WS_TMEAN;

    k1_fused<<<dim3(BB), dim3(256), 0, stream>>>(x, Wih, Whh, bih, bhh, s_mean, t_mean);
    k2_out  <<<dim3(4096), dim3(256), 0, stream>>>(s_mean, t_mean, (f32x4*)d_out);
}

// Round 11
// 48.459 us; speedup vs baseline: 1.2768x; 1.0280x over previous
//
#include <hip/hip_runtime.h>
#include <math.h>

#define BB   512
#define CC   3
#define HH   64
#define WW   32
#define HOUT 38
#define WOUT 16
#define HID  128
#define DD   114               // CC*HOUT
#define SEQP 120               // seq row pad: 60-float halves, 16B-aligned
#define WIHP 120               // Wih LDS row pad (words)
#define WHHP 132               // Whh LDS row pad (words); 132%32=4 -> banks spread
#define NPOOL (CC*HOUT*WOUT)   // 1824

typedef float f32x4 __attribute__((ext_vector_type(4)));

// fast tanh on the serial chain: exact saturation at +/-inf, ~1e-6 abs error
__device__ __forceinline__ float fast_tanh(float u) {
    return 1.f - 2.f / (__expf(2.f * u) + 1.f);
}

// ws layout (floats)
#define WS_SMEAN 0
#define WS_TMEAN 512

// ---- fused per-batch kernel ------------------------------------------------
// 256 threads = 4 waves. Wave w owns output rows k in [32w,32w+32); lane
// l: kl = 32w + (l&31), kc = l>>5 selects the K-half. Split-K partials
// combine via __shfl_xor(32) INSIDE the wave -> recurrence needs only ONE
// barrier per step (h publish). Whh staged in a single round (67.6 KB LDS).
__global__ __launch_bounds__(256, 2)
void k1_fused(const float* __restrict__ x,
              const float* __restrict__ Wih,
              const float* __restrict__ Whh,
              const float* __restrict__ bih,
              const float* __restrict__ bhh,
              float* __restrict__ s_mean,
              float* __restrict__ t_mean)
{
    __shared__ __align__(16) float wst[HID * WHHP];  // 67.6 KB; x / Wih / Whh
    __shared__ __align__(16) float seq[WOUT][SEQP];  // 7.7 KB
    __shared__ __align__(16) float hbuf[2][HID];     // 1 KB
    __shared__ float red[4];
    __shared__ int   rowl[HOUT];

    const int tid  = threadIdx.x;
    const int wid  = tid >> 6;
    const int lane = tid & 63;
    const int kl   = (wid << 5) | (lane & 31);   // owned output row
    const int kc   = lane >> 5;                  // K-half (0/1)
    const int b    = blockIdx.x;

    // --- issue x loads FIRST (oldest in vmcnt FIFO), then Wih prefetch ---
    f32x4 xpf[6];
    {
        const f32x4* xg = (const f32x4*)(x + (size_t)b * (CC*HH*WW));
        #pragma unroll
        for (int i = 0; i < 6; ++i) xpf[i] = xg[tid + 256*i];
    }
    f32x4 wihpf[14], wihtail;
    {
        const f32x4* wg = (const f32x4*)Wih;          // 3648 f4 total
        #pragma unroll
        for (int i = 0; i < 14; ++i) wihpf[i] = wg[tid + 256*i];
        if (tid < 64) wihtail = wg[3584 + tid];
    }

    // fractional-pool row starts (exact IEEE-f64 numpy match)
    if (tid < HOUT) {
        double alpha = (double)(HH - 2) / (double)(HOUT - 1);
        rowl[tid] = (tid < HOUT - 1)
            ? (int)(floor((tid + 0.5) * alpha) - floor(0.5 * alpha))
            : (HH - 2);
    }
    if (tid < HID) hbuf[0][tid] = 0.f;
    if (tid < 96)  seq[tid / 6][DD + tid % 6] = 0.f;  // zero pad cols [114,120)

    // --- write x to LDS (waits only on x loads; Wih stays in flight) ---
    {
        f32x4* xd = (f32x4*)wst;
        #pragma unroll
        for (int i = 0; i < 6; ++i) xd[tid + 256*i] = xpf[i];
    }
    __syncthreads();                                  // B1

    // --- pool (2x2 fractional max) + exact GELU -> seq; spatial sum ---
    float ps = 0.f;
    #pragma unroll
    for (int it = 0; it < 8; ++it) {
        int idx = tid + it*256;
        if (idx < NPOOL) {
            int c  = idx / (HOUT*WOUT);
            int r  = idx % (HOUT*WOUT);
            int ho = r / WOUT;
            int wo = r % WOUT;
            const float* p0 = &wst[c*(HH*WW) + rowl[ho]*WW + 2*wo];
            float m = fmaxf(fmaxf(p0[0], p0[1]), fmaxf(p0[WW], p0[WW+1]));
            ps += m;
            seq[wo][c*HOUT + ho] =
                0.5f * m * (1.f + erff(m * 0.70710678118654752440f));
        }
    }
    #pragma unroll
    for (int off = 32; off > 0; off >>= 1) ps += __shfl_down(ps, off);
    if (lane == 0) red[wid] = ps;
    __syncthreads();                                  // B2 (x reads done; wst reusable)
    if (tid == 0)
        s_mean[b] = (red[0] + red[1] + red[2] + red[3]) * (1.f / (float)NPOOL);

    // --- Wih: LDS writes from prefetched regs into padded rows [128][120] ---
    #pragma unroll
    for (int i = 0; i < 14; ++i) {
        int j = 4*(tid + 256*i);
        #pragma unroll
        for (int e = 0; e < 4; ++e) {
            int r  = (j + e) / DD;                    // const-div -> magic mul
            int cc = (j + e) - r*DD;
            wst[r*WIHP + cc] = wihpf[i][e];
        }
    }
    if (tid < 64) {
        int j = 4*(3584 + tid);
        #pragma unroll
        for (int e = 0; e < 4; ++e) {
            int r  = (j + e) / DD;
            int cc = (j + e) - r*DD;
            wst[r*WIHP + cc] = wihtail[e];
        }
    }
    for (int j = tid; j < HID*6; j += 256)            // zero cols [114,120)
        wst[(j/6)*WIHP + DD + (j % 6)] = 0.f;
    __syncthreads();                                  // B3

    // wih regs: K-half kc of Wih row kl (60 floats)
    f32x4 wih[15];
    {
        const f32x4* wr = (const f32x4*)&wst[kl*WIHP + kc*60];
        #pragma unroll
        for (int dd = 0; dd < 15; ++dd) wih[dd] = wr[dd];
    }

    // --- issue full Whh prefetch (16 f4); latency hides under projection ---
    f32x4 whhpf[16];
    {
        const f32x4* hg = (const f32x4*)Whh;          // 4096 f4
        #pragma unroll
        for (int i = 0; i < 16; ++i) whhpf[i] = hg[tid + 256*i];
    }

    // --- projection: zreg[t] complete in BOTH kc lanes via shfl_xor ---
    float zreg[WOUT];
    #pragma unroll
    for (int t = 0; t < WOUT; ++t) {
        const f32x4* a4 = (const f32x4*)&seq[t][kc*60];   // 2 addr streams/wave
        float s0 = 0.f, s1 = 0.f, s2 = 0.f, s3 = 0.f;
        #pragma unroll
        for (int dd = 0; dd < 15; ++dd) {
            f32x4 a = a4[dd];
            s0 = fmaf(wih[dd].x, a.x, s0);
            s1 = fmaf(wih[dd].y, a.y, s1);
            s2 = fmaf(wih[dd].z, a.z, s2);
            s3 = fmaf(wih[dd].w, a.w, s3);
        }
        float p = (s0 + s1) + (s2 + s3);
        zreg[t] = p + __shfl_xor(p, 32);
    }
    {
        const float bias = bih[kl] + bhh[kl];
        #pragma unroll
        for (int t = 0; t < WOUT; ++t) zreg[t] += bias;
    }
    __syncthreads();                                  // B4 (wih copies done; wst free)

    // --- Whh: ONE staging round into padded rows [128][132] ---
    #pragma unroll
    for (int i = 0; i < 16; ++i) {
        int j4 = tid + 256*i;
        *(f32x4*)&wst[(j4 >> 5)*WHHP + ((j4 & 31) << 2)] = whhpf[i];
    }
    __syncthreads();                                  // B5
    f32x4 whh[16];
    {
        const f32x4* wr = (const f32x4*)&wst[kl*WHHP + (kc << 6)];
        #pragma unroll
        for (int dd = 0; dd < 16; ++dd) whh[dd] = wr[dd];
    }

    // --- 16-step recurrence: intra-wave shfl combine, ONE barrier/step ---
    float hsum = 0.f;
    #pragma unroll
    for (int t = 0; t < WOUT; ++t) {
        const int cur = t & 1, nxt = cur ^ 1;
        const f32x4* h4 = (const f32x4*)&hbuf[cur][kc << 6];  // bcast (2-way)
        float s0 = 0.f, s1 = 0.f, s2 = 0.f, s3 = 0.f;
        #pragma unroll
        for (int dd = 0; dd < 16; ++dd) {
            f32x4 hv = h4[dd];
            s0 = fmaf(whh[dd].x, hv.x, s0);
            s1 = fmaf(whh[dd].y, hv.y, s1);
            s2 = fmaf(whh[dd].z, hv.z, s2);
            s3 = fmaf(whh[dd].w, hv.w, s3);
        }
        float p  = (s0 + s1) + (s2 + s3);
        float u  = zreg[t] + p + __shfl_xor(p, 32);
        float hn = fast_tanh(u);
        hsum += hn;
        if (kc == 0) hbuf[nxt][kl] = hn;              // 32 b32/wave, conflict-free
        __syncthreads();                              // h publish (one per step)
    }
    if (kc == 0) t_mean[b*HID + kl] = fast_tanh(hsum * (1.f / 16.f));
}

// ---- k2: block (i, sub) writes out[i, 0, sub*2048 .. +2048) f4 -------------
__global__ __launch_bounds__(256)
void k2_out(const float* __restrict__ s_mean,
            const float* __restrict__ t_mean,
            f32x4* __restrict__ out)
{
    const int i   = blockIdx.x >> 3;           // batch row (512)
    const int sub = blockIdx.x & 7;            // eighth of a row
    const float s = s_mean[i];
    const f32x4* t4 = (const f32x4*)t_mean + sub*2048;
    f32x4*       o  = out + (size_t)i*16384 + sub*2048;
    const int tid = threadIdx.x;
    #pragma unroll
    for (int j = 0; j < 8; ++j) {
        int idx = tid + j*256;
        o[idx] = s * t4[idx];
    }
}

extern "C" void kernel_launch(void* const* d_in, const int* in_sizes, int n_in,
                              void* d_out, int out_size, void* d_ws, size_t ws_size,
                              hipStream_t stream)
{
    const float* x   = (const float*)d_in[0];
    const float* Wih = (const float*)d_in[1];
    const float* Whh = (const float*)d_in[2];
    const float* bih = (const float*)d_in[3];
    const float* bhh = (const float*)d_in[4];

    float* ws     = (float*)d_ws;
    float* s_mean = ws + WS_SMEAN;
    float* t_mean = ws + WS_TMEAN;

    k1_fused<<<dim3(BB), dim3(256), 0, stream>>>(x, Wih, Whh, bih, bhh, s_mean, t_mean);
    k2_out  <<<dim3(4096), dim3(256), 0, stream>>>(s_mean, t_mean, (f32x4*)d_out);
}